// Round 5
// baseline (520.417 us; speedup 1.0000x reference)
//
#include <hip/hip_runtime.h>
#include <math.h>

#define D_IN 5
#define H 64
#define CAP 1024  // bucket capacity (64-node buckets, avg fill ~640, Poisson sigma ~25)

using f32x4 = __attribute__((ext_vector_type(4))) float;
using short8 = __attribute__((ext_vector_type(8))) short;

__device__ inline short f2bf(float f) {
  unsigned u = __builtin_bit_cast(unsigned, f);
  u += 0x7fffu + ((u >> 16) & 1u);  // round-to-nearest-even
  return (short)(u >> 16);
}
__device__ inline float bf2f(short s) {
  return __builtin_bit_cast(float, ((unsigned)(unsigned short)s) << 16);
}
__device__ inline short8 cvt8(f32x4 a, f32x4 b) {
  short8 r;
  r[0] = f2bf(a[0]); r[1] = f2bf(a[1]); r[2] = f2bf(a[2]); r[3] = f2bf(a[3]);
  r[4] = f2bf(b[0]); r[5] = f2bf(b[1]); r[6] = f2bf(b[2]); r[7] = f2bf(b[3]);
  return r;
}

// ---------------- input projection ----------------
__global__ __launch_bounds__(256) void proj_kernel(
    const float* __restrict__ x, const float* __restrict__ W,
    const float* __restrict__ b, short* __restrict__ out, int n) {
  __shared__ float Ws[D_IN * H];
  __shared__ float bs[H];
  int t = threadIdx.x;
  for (int i = t; i < D_IN * H; i += 256) Ws[i] = W[i];
  if (t < H) bs[t] = b[t];
  __syncthreads();
  int idx = blockIdx.x * 256 + t;
  int node = idx >> 6;
  int h = idx & 63;
  if (node >= n) return;
  const float* xr = x + (size_t)node * D_IN;
  float acc = bs[h];
#pragma unroll
  for (int d = 0; d < D_IN; ++d) acc = fmaf(xr[d], Ws[d * H + h], acc);
  out[(size_t)node * H + h] = f2bf(acc);
}

// ---------------- CSR build v2: bucketed counting sort ----------------
// pass 1: scatter (payload,node) pairs into 64-node buckets at atomic tails.
// D side: bucket by dst (payload=src) -> feeds col_mft; S side: bucket by src (payload=dst).
__global__ __launch_bounds__(256) void scatter_kernel(
    const int* __restrict__ src, const int* __restrict__ dst,
    int* cntD, int* cntS,
    uint2* __restrict__ bufD, uint2* __restrict__ bufS, int E) {
  int e0 = (blockIdx.x * 256 + threadIdx.x) * 4;
  if (e0 >= E) return;
  if (e0 + 4 <= E) {
    int4 s4 = *(const int4*)(src + e0);
    int4 d4 = *(const int4*)(dst + e0);
    // issue all 8 atomics before any dependent store
    int pD0 = atomicAdd(&cntD[d4.x >> 6], 1);
    int pD1 = atomicAdd(&cntD[d4.y >> 6], 1);
    int pD2 = atomicAdd(&cntD[d4.z >> 6], 1);
    int pD3 = atomicAdd(&cntD[d4.w >> 6], 1);
    int pS0 = atomicAdd(&cntS[s4.x >> 6], 1);
    int pS1 = atomicAdd(&cntS[s4.y >> 6], 1);
    int pS2 = atomicAdd(&cntS[s4.z >> 6], 1);
    int pS3 = atomicAdd(&cntS[s4.w >> 6], 1);
    if (pD0 < CAP) bufD[(size_t)(d4.x >> 6) * CAP + pD0] = make_uint2(s4.x, d4.x);
    if (pD1 < CAP) bufD[(size_t)(d4.y >> 6) * CAP + pD1] = make_uint2(s4.y, d4.y);
    if (pD2 < CAP) bufD[(size_t)(d4.z >> 6) * CAP + pD2] = make_uint2(s4.z, d4.z);
    if (pD3 < CAP) bufD[(size_t)(d4.w >> 6) * CAP + pD3] = make_uint2(s4.w, d4.w);
    if (pS0 < CAP) bufS[(size_t)(s4.x >> 6) * CAP + pS0] = make_uint2(d4.x, s4.x);
    if (pS1 < CAP) bufS[(size_t)(s4.y >> 6) * CAP + pS1] = make_uint2(d4.y, s4.y);
    if (pS2 < CAP) bufS[(size_t)(s4.z >> 6) * CAP + pS2] = make_uint2(d4.z, s4.z);
    if (pS3 < CAP) bufS[(size_t)(s4.w >> 6) * CAP + pS3] = make_uint2(d4.w, s4.w);
  } else {
    for (int i = 0; i < 4; ++i) {
      int e = e0 + i;
      if (e < E) {
        int s = src[e], d = dst[e];
        int pD = atomicAdd(&cntD[d >> 6], 1);
        int pS = atomicAdd(&cntS[s >> 6], 1);
        if (pD < CAP) bufD[(size_t)(d >> 6) * CAP + pD] = make_uint2(s, d);
        if (pS < CAP) bufS[(size_t)(s >> 6) * CAP + pS] = make_uint2(d, s);
      }
    }
  }
}

// pass 2: exclusive-scan bucket counts (block 0 -> D, block 1 -> S); chunked w/ carry
__global__ __launch_bounds__(1024) void bucket_scan_kernel(
    const int* __restrict__ cntD, int* __restrict__ BoffD, int nbD,
    const int* __restrict__ cntS, int* __restrict__ BoffS, int nbS) {
  const int* cnt = blockIdx.x ? cntS : cntD;
  int* Boff = blockIdx.x ? BoffS : BoffD;
  int nb = blockIdx.x ? nbS : nbD;
  __shared__ int tmp[1024];
  __shared__ int carry;
  int t = threadIdx.x;
  if (t == 0) carry = 0;
  __syncthreads();
  for (int base = 0; base < nb; base += 1024) {
    int i = base + t;
    int v = (i < nb) ? min(cnt[i], CAP) : 0;
    tmp[t] = v;
    __syncthreads();
    for (int s = 1; s < 1024; s <<= 1) {
      int add = (t >= s) ? tmp[t - s] : 0;
      __syncthreads();
      tmp[t] += add;
      __syncthreads();
    }
    if (i < nb) Boff[i] = carry + tmp[t] - v;
    __syncthreads();
    if (t == 1023) carry = carry + tmp[1023];
    __syncthreads();
  }
  if (t == 0) Boff[nb] = carry;
}

// pass 3: per-bucket finalize — LDS histogram + wave prefix scan -> off[], then
// scatter col entries into the bucket's contiguous (L2-local) window.
__global__ __launch_bounds__(256) void finalize_kernel(
    const uint2* __restrict__ bufD, const int* __restrict__ BoffD, int nbD, int n_mft,
    int* __restrict__ off_mft, int* __restrict__ col_mft,
    const uint2* __restrict__ bufS, const int* __restrict__ BoffS, int n_mch,
    int* __restrict__ off_mch, int* __restrict__ col_mch, int E) {
  int b = blockIdx.x;
  const uint2* buf;
  const int* Boff;
  int n;
  int* off;
  int* col;
  if (b >= nbD) {
    b -= nbD;
    buf = bufS; Boff = BoffS; n = n_mch; off = off_mch; col = col_mch;
  } else {
    buf = bufD; Boff = BoffD; n = n_mft; off = off_mft; col = col_mft;
  }
  int base = Boff[b], next = Boff[b + 1];
  int cnt = next - base;
  const uint2* mybuf = buf + (size_t)b * CAP;

  __shared__ int hist[64];
  __shared__ int curs[64];
  int t = threadIdx.x;
  if (t < 64) hist[t] = 0;
  __syncthreads();
  for (int j = t; j < cnt; j += 256) {
    uint2 p = mybuf[j];
    atomicAdd(&hist[p.y & 63], 1);
  }
  __syncthreads();
  if (t < 64) {  // wave 0: prefix scan of 64 degrees
    int h = hist[t];
    int x = h;
#pragma unroll
    for (int s = 1; s < 64; s <<= 1) {
      int y = __shfl(x, t - s);
      if (t >= s) x += y;
    }
    int pre = x - h;  // exclusive prefix within bucket
    int gnode = b * 64 + t;
    if (gnode < n) {
      off[gnode] = base + pre;
      if (gnode == n - 1) off[n] = E;
    }
    curs[t] = base + pre;
  }
  __syncthreads();
  for (int j = t; j < cnt; j += 256) {
    uint2 p = mybuf[j];
    int pos = atomicAdd(&curs[p.y & 63], 1);
    col[pos] = (int)p.x;
  }
}

// ---------------- fused SAGE via MFMA (bf16 feats), both directions in one launch ------
template <bool RELU>
__global__ __launch_bounds__(256) void sage_dual_kernel(
    const short* __restrict__ xsrcA, const short* __restrict__ xdstA,
    const int* __restrict__ offA, const int* __restrict__ colA,
    const float* __restrict__ WlA, const float* __restrict__ blA,
    const float* __restrict__ WrA, short* __restrict__ outA, int nA, int blkA,
    const short* __restrict__ xsrcB, const short* __restrict__ xdstB,
    const int* __restrict__ offB, const int* __restrict__ colB,
    const float* __restrict__ WlB, const float* __restrict__ blB,
    const float* __restrict__ WrB, short* __restrict__ outB, int nB) {
  bool isB = ((int)blockIdx.x >= blkA);
  int bid = isB ? (int)blockIdx.x - blkA : (int)blockIdx.x;
  const short* xsrc = isB ? xsrcB : xsrcA;
  const short* xdst = isB ? xdstB : xdstA;
  const int* off = isB ? offB : offA;
  const int* col = isB ? colB : colA;
  const float* Wl = isB ? WlB : WlA;
  const float* bl = isB ? blB : blA;
  const float* Wr = isB ? WrB : WrA;
  short* out = isB ? outB : outA;
  int n_dst = isB ? nB : nA;

  int t = threadIdx.x;
  int wave = t >> 6, lane = t & 63;
  int g = lane >> 4, c = lane & 15;

  short8 bw[4][4];
#pragma unroll
  for (int kt = 0; kt < 4; ++kt) {
    const float* Wsrc = (kt < 2) ? Wl : Wr;
    int kbase = (kt & 1) * 32 + 8 * g;
#pragma unroll
    for (int n = 0; n < 4; ++n) {
      short8 w;
#pragma unroll
      for (int j = 0; j < 8; ++j)
        w[j] = f2bf(Wsrc[(kbase + j) * H + 16 * n + c]);
      bw[kt][n] = w;
    }
  }
  float blv[4];
#pragma unroll
  for (int n = 0; n < 4; ++n) blv[n] = bl[16 * n + c];

  int node0 = (bid * 4 + wave) * 16;
  if (node0 >= n_dst) return;

  int mynode = node0 + c;
  int nd = (mynode < n_dst) ? mynode : 0;

  float m[16];
#pragma unroll
  for (int i = 0; i < 16; ++i) m[i] = 0.f;
  int beg = off[nd], end = off[nd + 1];
  int n_nb = end - beg;
  if (n_nb > 0) {
    int idx_c = col[beg];
    int idx_n = (n_nb > 1) ? col[beg + 1] : 0;
    const short8* pc = (const short8*)(xsrc + (size_t)idx_c * H + 8 * g);
    short8 u0 = pc[0], u1 = pc[4];
    for (int j = 1; j < n_nb; ++j) {
      int idx_n2 = (j + 1 < n_nb) ? col[beg + j + 1] : 0;
      const short8* pn = (const short8*)(xsrc + (size_t)idx_n * H + 8 * g);
      short8 v0 = pn[0], v1 = pn[4];
#pragma unroll
      for (int i = 0; i < 8; ++i) {
        m[i] += bf2f(u0[i]);
        m[8 + i] += bf2f(u1[i]);
      }
      u0 = v0;
      u1 = v1;
      idx_n = idx_n2;
    }
#pragma unroll
    for (int i = 0; i < 8; ++i) {
      m[i] += bf2f(u0[i]);
      m[8 + i] += bf2f(u1[i]);
    }
  }
  float invd = (n_nb > 0) ? 1.f / (float)n_nb : 1.f;
  f32x4 m0, m1, m2, m3;
#pragma unroll
  for (int i = 0; i < 4; ++i) {
    m0[i] = m[i] * invd;
    m1[i] = m[4 + i] * invd;
    m2[i] = m[8 + i] * invd;
    m3[i] = m[12 + i] * invd;
  }
  const short8* pr = (const short8*)(xdst + (size_t)nd * H + 8 * g);

  short8 af[4];
  af[0] = cvt8(m0, m1);
  af[1] = cvt8(m2, m3);
  af[2] = pr[0];
  af[3] = pr[4];

  f32x4 zero4 = {0.f, 0.f, 0.f, 0.f};
  f32x4 acc[4];
#pragma unroll
  for (int n = 0; n < 4; ++n) acc[n] = zero4;
#pragma unroll
  for (int kt = 0; kt < 4; ++kt)
#pragma unroll
    for (int n = 0; n < 4; ++n)
      acc[n] = __builtin_amdgcn_mfma_f32_16x16x32_bf16(af[kt], bw[kt][n], acc[n], 0, 0, 0);

#pragma unroll
  for (int n = 0; n < 4; ++n)
#pragma unroll
    for (int r = 0; r < 4; ++r) {
      float o = acc[n][r] + blv[n];
      if (RELU) o = fmaxf(o, 0.f);
      int row = node0 + 4 * g + r;
      if (row < n_dst) out[(size_t)row * H + 16 * n + c] = f2bf(o);
    }
}

// ---------------- edge classifier via MFMA (bf16 gathers) --------------
__global__ __launch_bounds__(256) void edge_mlp_mfma_kernel(
    const short* __restrict__ mch2, const short* __restrict__ mft2,
    const int* __restrict__ src, const int* __restrict__ dst,
    const float* __restrict__ W1, const float* __restrict__ b1,
    const float* __restrict__ W2, const float* __restrict__ b2,
    float* __restrict__ out, int E) {
  int t = threadIdx.x;
  int wave = t >> 6, lane = t & 63;
  int g = lane >> 4, c = lane & 15;

  short8 bw[4][4];
#pragma unroll
  for (int kt = 0; kt < 4; ++kt) {
#pragma unroll
    for (int n = 0; n < 4; ++n) {
      short8 w;
#pragma unroll
      for (int j = 0; j < 8; ++j)
        w[j] = f2bf(W1[(32 * kt + 8 * g + j) * H + 16 * n + c]);
      bw[kt][n] = w;
    }
  }
  float b1v[4], w2v[4];
#pragma unroll
  for (int n = 0; n < 4; ++n) { b1v[n] = b1[16 * n + c]; w2v[n] = W2[16 * n + c]; }
  float b2v = b2[0];
  f32x4 zero4 = {0.f, 0.f, 0.f, 0.f};

  int ntiles = (E + 15) >> 4;
  for (int tile = blockIdx.x * 4 + wave; tile < ntiles; tile += gridDim.x * 4) {
    int e0 = tile * 16;
    int e = e0 + c;
    int ee = (e < E) ? e : E - 1;
    int s = src[ee], d = dst[ee];
    const short8* pa = (const short8*)(mch2 + (size_t)s * H + 8 * g);
    const short8* pb = (const short8*)(mft2 + (size_t)d * H + 8 * g);
    short8 af[4];
    af[0] = pa[0];
    af[1] = pa[4];
    af[2] = pb[0];
    af[3] = pb[4];

    f32x4 acc[4];
#pragma unroll
    for (int n = 0; n < 4; ++n) acc[n] = zero4;
#pragma unroll
    for (int kt = 0; kt < 4; ++kt)
#pragma unroll
      for (int n = 0; n < 4; ++n)
        acc[n] = __builtin_amdgcn_mfma_f32_16x16x32_bf16(af[kt], bw[kt][n], acc[n], 0, 0, 0);

    float part[4];
#pragma unroll
    for (int r = 0; r < 4; ++r) {
      float sum = 0.f;
#pragma unroll
      for (int n = 0; n < 4; ++n) {
        float v = acc[n][r] + b1v[n];
        v = fmaxf(v, 0.f);
        sum = fmaf(v, w2v[n], sum);
      }
      part[r] = sum;
    }
#pragma unroll
    for (int r = 0; r < 4; ++r) {
      part[r] += __shfl_xor(part[r], 1);
      part[r] += __shfl_xor(part[r], 2);
      part[r] += __shfl_xor(part[r], 4);
      part[r] += __shfl_xor(part[r], 8);
    }
    if (c < 4) {
      int eo = e0 + 4 * g + c;
      float v = (c == 0) ? part[0] : (c == 1) ? part[1] : (c == 2) ? part[2] : part[3];
      if (eo < E) out[eo] = 1.f / (1.f + expf(-(v + b2v)));
    }
  }
}

extern "C" void kernel_launch(void* const* d_in, const int* in_sizes, int n_in,
                              void* d_out, int out_size, void* d_ws, size_t ws_size,
                              hipStream_t stream) {
  const float* x_mch = (const float*)d_in[0];
  const float* x_mft = (const float*)d_in[1];
  const int* eidx = (const int*)d_in[2];
  const int E = in_sizes[2] / 2;
  const int* src = eidx;
  const int* dst = eidx + E;
  const float* W_mch = (const float*)d_in[3];
  const float* b_mch = (const float*)d_in[4];
  const float* W_mft = (const float*)d_in[5];
  const float* b_mft = (const float*)d_in[6];
  const float* c1m_Wl = (const float*)d_in[7];
  const float* c1m_bl = (const float*)d_in[8];
  const float* c1m_Wr = (const float*)d_in[9];
  const float* c1r_Wl = (const float*)d_in[10];
  const float* c1r_bl = (const float*)d_in[11];
  const float* c1r_Wr = (const float*)d_in[12];
  const float* c2m_Wl = (const float*)d_in[13];
  const float* c2m_bl = (const float*)d_in[14];
  const float* c2m_Wr = (const float*)d_in[15];
  const float* c2r_Wl = (const float*)d_in[16];
  const float* c2r_bl = (const float*)d_in[17];
  const float* c2r_Wr = (const float*)d_in[18];
  const float* ec_W1 = (const float*)d_in[19];
  const float* ec_b1 = (const float*)d_in[20];
  const float* ec_W2 = (const float*)d_in[21];
  const float* ec_b2 = (const float*)d_in[22];

  const int n_mch = in_sizes[0] / D_IN;
  const int n_mft = in_sizes[1] / D_IN;

  // ---- workspace layout ----
  char* ws = (char*)d_ws;
  auto alloc = [&](size_t bytes) {
    char* p = ws;
    ws += (bytes + 255) & ~(size_t)255;
    return p;
  };
  short* h_mch = (short*)alloc((size_t)n_mch * H * 2);
  short* h_mft = (short*)alloc((size_t)n_mft * H * 2);
  short* mch1 = (short*)alloc((size_t)n_mch * H * 2);
  short* mft1 = (short*)alloc((size_t)n_mft * H * 2);
  short* mch2 = (short*)alloc((size_t)n_mch * H * 2);
  short* mft2 = (short*)alloc((size_t)n_mft * H * 2);
  int* off_mch = (int*)alloc(((size_t)n_mch + 1) * 4);
  int* off_mft = (int*)alloc(((size_t)n_mft + 1) * 4);
  int* col_mch = (int*)alloc((size_t)E * 4);
  int* col_mft = (int*)alloc((size_t)E * 4);
  const int nbD = (n_mft + 63) / 64;  // buckets by dst (mft side)
  const int nbS = (n_mch + 63) / 64;  // buckets by src (mch side)
  int* cnt = (int*)alloc(((size_t)nbD + nbS) * 4);
  int* cntD = cnt;
  int* cntS = cnt + nbD;
  int* BoffD = (int*)alloc(((size_t)nbD + 1) * 4);
  int* BoffS = (int*)alloc(((size_t)nbS + 1) * 4);
  uint2* bufD = (uint2*)alloc((size_t)nbD * CAP * 8);
  uint2* bufS = (uint2*)alloc((size_t)nbS * CAP * 8);

  float* out = (float*)d_out;

  // ---- CSR build v2 ----
  hipMemsetAsync(cnt, 0, ((size_t)nbD + nbS) * 4, stream);
  scatter_kernel<<<(E + 1023) / 1024, 256, 0, stream>>>(src, dst, cntD, cntS,
                                                        bufD, bufS, E);
  bucket_scan_kernel<<<2, 1024, 0, stream>>>(cntD, BoffD, nbD, cntS, BoffS, nbS);
  finalize_kernel<<<nbD + nbS, 256, 0, stream>>>(
      bufD, BoffD, nbD, n_mft, off_mft, col_mft,
      bufS, BoffS, n_mch, off_mch, col_mch, E);

  // ---- input projections ----
  {
    int blk = ((n_mch * H) + 255) / 256;
    proj_kernel<<<blk, 256, 0, stream>>>(x_mch, W_mch, b_mch, h_mch, n_mch);
    blk = ((n_mft * H) + 255) / 256;
    proj_kernel<<<blk, 256, 0, stream>>>(x_mft, W_mft, b_mft, h_mft, n_mft);
  }

  // ---- convs (MFMA, both directions per launch) ----
  {
    int tiles_mft = (n_mft + 15) / 16;
    int tiles_mch = (n_mch + 15) / 16;
    int blkA = (tiles_mft + 3) / 4;
    int blkB = (tiles_mch + 3) / 4;
    sage_dual_kernel<true><<<blkA + blkB, 256, 0, stream>>>(
        h_mch, h_mft, off_mft, col_mft, c1m_Wl, c1m_bl, c1m_Wr, mft1, n_mft, blkA,
        h_mft, h_mch, off_mch, col_mch, c1r_Wl, c1r_bl, c1r_Wr, mch1, n_mch);
    sage_dual_kernel<false><<<blkA + blkB, 256, 0, stream>>>(
        mch1, mft1, off_mft, col_mft, c2m_Wl, c2m_bl, c2m_Wr, mft2, n_mft, blkA,
        mft1, mch1, off_mch, col_mch, c2r_Wl, c2r_bl, c2r_Wr, mch2, n_mch);
  }

  // ---- edge classifier (MFMA) ----
  {
    edge_mlp_mfma_kernel<<<2048, 256, 0, stream>>>(mch2, mft2, src, dst,
                                                   ec_W1, ec_b1, ec_W2, ec_b2, out, E);
  }
}

// Round 6
// 433.118 us; speedup vs baseline: 1.2016x; 1.2016x over previous
//
#include <hip/hip_runtime.h>
#include <math.h>

#define D_IN 5
#define H 64
#define PART_SHIFT 4  // partition = (node >> 4) & 7 : 16-node groups -> one 64B cur line per partition

using f32x4 = __attribute__((ext_vector_type(4))) float;
using short8 = __attribute__((ext_vector_type(8))) short;

__device__ inline short f2bf(float f) {
  unsigned u = __builtin_bit_cast(unsigned, f);
  u += 0x7fffu + ((u >> 16) & 1u);  // round-to-nearest-even
  return (short)(u >> 16);
}
__device__ inline float bf2f(short s) {
  return __builtin_bit_cast(float, ((unsigned)(unsigned short)s) << 16);
}
__device__ inline short8 cvt8(f32x4 a, f32x4 b) {
  short8 r;
  r[0] = f2bf(a[0]); r[1] = f2bf(a[1]); r[2] = f2bf(a[2]); r[3] = f2bf(a[3]);
  r[4] = f2bf(b[0]); r[5] = f2bf(b[1]); r[6] = f2bf(b[2]); r[7] = f2bf(b[3]);
  return r;
}

// ---------------- input projection ----------------
__global__ __launch_bounds__(256) void proj_kernel(
    const float* __restrict__ x, const float* __restrict__ W,
    const float* __restrict__ b, short* __restrict__ out, int n) {
  __shared__ float Ws[D_IN * H];
  __shared__ float bs[H];
  int t = threadIdx.x;
  for (int i = t; i < D_IN * H; i += 256) Ws[i] = W[i];
  if (t < H) bs[t] = b[t];
  __syncthreads();
  int idx = blockIdx.x * 256 + t;
  int node = idx >> 6;
  int h = idx & 63;
  if (node >= n) return;
  const float* xr = x + (size_t)node * D_IN;
  float acc = bs[h];
#pragma unroll
  for (int d = 0; d < D_IN; ++d) acc = fmaf(xr[d], Ws[d * H + h], acc);
  out[(size_t)node * H + h] = f2bf(acc);
}

// ---------------- CSR build v3: XCD-partitioned degree + fill ----------------
// Cohort c = blockIdx&7 (maps to one XCD under round-robin dispatch) processes only
// nodes with ((node>>PART_SHIFT)&7)==c, so every cur/col cache line is written by a
// single XCD's L2 -> full-line writebacks, no cross-XCD bouncing.
__global__ __launch_bounds__(256) void degree_part_kernel(
    const int* __restrict__ src, const int* __restrict__ dst,
    int* cur_mch, int* cur_mft, int E) {
  int cohort = blockIdx.x & 7;
  int w = blockIdx.x >> 3;
  int nw = gridDim.x >> 3;
  int stride = nw * 256 * 4;
  for (int e0 = (w * 256 + (int)threadIdx.x) * 4; e0 < E; e0 += stride) {
    if (e0 + 4 <= E) {
      int4 s4 = *(const int4*)(src + e0);
      int4 d4 = *(const int4*)(dst + e0);
      if (((s4.x >> PART_SHIFT) & 7) == cohort) atomicAdd(&cur_mch[s4.x], 1);
      if (((s4.y >> PART_SHIFT) & 7) == cohort) atomicAdd(&cur_mch[s4.y], 1);
      if (((s4.z >> PART_SHIFT) & 7) == cohort) atomicAdd(&cur_mch[s4.z], 1);
      if (((s4.w >> PART_SHIFT) & 7) == cohort) atomicAdd(&cur_mch[s4.w], 1);
      if (((d4.x >> PART_SHIFT) & 7) == cohort) atomicAdd(&cur_mft[d4.x], 1);
      if (((d4.y >> PART_SHIFT) & 7) == cohort) atomicAdd(&cur_mft[d4.y], 1);
      if (((d4.z >> PART_SHIFT) & 7) == cohort) atomicAdd(&cur_mft[d4.z], 1);
      if (((d4.w >> PART_SHIFT) & 7) == cohort) atomicAdd(&cur_mft[d4.w], 1);
    } else {
      for (int i = 0; i < 4; ++i) {
        int e = e0 + i;
        if (e < E) {
          int s = src[e], d = dst[e];
          if (((s >> PART_SHIFT) & 7) == cohort) atomicAdd(&cur_mch[s], 1);
          if (((d >> PART_SHIFT) & 7) == cohort) atomicAdd(&cur_mft[d], 1);
        }
      }
    }
  }
}

// phase 1: per-block (1024 elems) sums for both degree arrays
__global__ __launch_bounds__(256) void block_sum_kernel(
    const int* __restrict__ deg0, int n0,
    const int* __restrict__ deg1, int n1,
    int* __restrict__ bsum, int nb0) {
  int b = blockIdx.x;
  bool a1 = (b >= nb0);
  const int* deg = a1 ? deg1 : deg0;
  int n = a1 ? n1 : n0;
  int base = (a1 ? b - nb0 : b) * 1024;
  int t = threadIdx.x;
  int s = 0;
#pragma unroll
  for (int i = 0; i < 4; ++i) {
    int idx = base + t * 4 + i;
    if (idx < n) s += deg[idx];
  }
  __shared__ int red[256];
  red[t] = s;
  __syncthreads();
  for (int st = 128; st; st >>= 1) {
    if (t < st) red[t] += red[t + st];
    __syncthreads();
  }
  if (t == 0) bsum[b] = red[0];
}

// phase 2: exclusive-scan the block sums
__global__ __launch_bounds__(512) void bsum_scan_kernel(int* bsum, int nb0, int nb1) {
  int lo = blockIdx.x ? nb0 : 0;
  int nb = blockIdx.x ? nb1 : nb0;
  __shared__ int tmp[512];
  int t = threadIdx.x;
  int v = (t < nb) ? bsum[lo + t] : 0;
  tmp[t] = v;
  __syncthreads();
  for (int s = 1; s < 512; s <<= 1) {
    int add = (t >= s) ? tmp[t - s] : 0;
    __syncthreads();
    tmp[t] += add;
    __syncthreads();
  }
  if (t < nb) bsum[lo + t] = tmp[t] - v;  // exclusive
}

// phase 3: per-block scan + write off[] and cur[] (=off). deg aliases cur.
__global__ __launch_bounds__(256) void scan_write_kernel(
    const int* __restrict__ deg0, int* __restrict__ off0, int* __restrict__ cur0, int n0,
    const int* __restrict__ deg1, int* __restrict__ off1, int* __restrict__ cur1, int n1,
    const int* __restrict__ bsum, int nb0, int E) {
  int b = blockIdx.x;
  bool a1 = (b >= nb0);
  const int* deg = a1 ? deg1 : deg0;
  int* off = a1 ? off1 : off0;
  int* cur = a1 ? cur1 : cur0;
  int n = a1 ? n1 : n0;
  int base = (a1 ? b - nb0 : b) * 1024;
  int t = threadIdx.x;
  int v[4];
  int s = 0;
#pragma unroll
  for (int i = 0; i < 4; ++i) {
    int idx = base + t * 4 + i;
    v[i] = (idx < n) ? deg[idx] : 0;
    s += v[i];
  }
  __shared__ int tmp[256];
  tmp[t] = s;
  __syncthreads();
  for (int st = 1; st < 256; st <<= 1) {
    int add = (t >= st) ? tmp[t - st] : 0;
    __syncthreads();
    tmp[t] += add;
    __syncthreads();
  }
  int run = bsum[b] + tmp[t] - s;
#pragma unroll
  for (int i = 0; i < 4; ++i) {
    int idx = base + t * 4 + i;
    if (idx < n) {
      off[idx] = run;
      cur[idx] = run;
      run += v[i];
      if (idx == n - 1) off[n] = E;
    }
  }
}

// XCD-partitioned fill: cohort handles only its node partition on each side.
__global__ __launch_bounds__(256) void fill_part_kernel(
    const int* __restrict__ src, const int* __restrict__ dst,
    int* cur_mch, int* cur_mft,
    int* __restrict__ col_mch, int* __restrict__ col_mft, int E) {
  int cohort = blockIdx.x & 7;
  int w = blockIdx.x >> 3;
  int nw = gridDim.x >> 3;
  int stride = nw * 256 * 4;
  for (int e0 = (w * 256 + (int)threadIdx.x) * 4; e0 < E; e0 += stride) {
    if (e0 + 4 <= E) {
      int4 s4 = *(const int4*)(src + e0);
      int4 d4 = *(const int4*)(dst + e0);
      if (((d4.x >> PART_SHIFT) & 7) == cohort) col_mft[atomicAdd(&cur_mft[d4.x], 1)] = s4.x;
      if (((d4.y >> PART_SHIFT) & 7) == cohort) col_mft[atomicAdd(&cur_mft[d4.y], 1)] = s4.y;
      if (((d4.z >> PART_SHIFT) & 7) == cohort) col_mft[atomicAdd(&cur_mft[d4.z], 1)] = s4.z;
      if (((d4.w >> PART_SHIFT) & 7) == cohort) col_mft[atomicAdd(&cur_mft[d4.w], 1)] = s4.w;
      if (((s4.x >> PART_SHIFT) & 7) == cohort) col_mch[atomicAdd(&cur_mch[s4.x], 1)] = d4.x;
      if (((s4.y >> PART_SHIFT) & 7) == cohort) col_mch[atomicAdd(&cur_mch[s4.y], 1)] = d4.y;
      if (((s4.z >> PART_SHIFT) & 7) == cohort) col_mch[atomicAdd(&cur_mch[s4.z], 1)] = d4.z;
      if (((s4.w >> PART_SHIFT) & 7) == cohort) col_mch[atomicAdd(&cur_mch[s4.w], 1)] = d4.w;
    } else {
      for (int i = 0; i < 4; ++i) {
        int e = e0 + i;
        if (e < E) {
          int s = src[e], d = dst[e];
          if (((d >> PART_SHIFT) & 7) == cohort) col_mft[atomicAdd(&cur_mft[d], 1)] = s;
          if (((s >> PART_SHIFT) & 7) == cohort) col_mch[atomicAdd(&cur_mch[s], 1)] = d;
        }
      }
    }
  }
}

// ---------------- fused SAGE via MFMA (bf16 feats), both directions in one launch ------
template <bool RELU>
__global__ __launch_bounds__(256) void sage_dual_kernel(
    const short* __restrict__ xsrcA, const short* __restrict__ xdstA,
    const int* __restrict__ offA, const int* __restrict__ colA,
    const float* __restrict__ WlA, const float* __restrict__ blA,
    const float* __restrict__ WrA, short* __restrict__ outA, int nA, int blkA,
    const short* __restrict__ xsrcB, const short* __restrict__ xdstB,
    const int* __restrict__ offB, const int* __restrict__ colB,
    const float* __restrict__ WlB, const float* __restrict__ blB,
    const float* __restrict__ WrB, short* __restrict__ outB, int nB) {
  bool isB = ((int)blockIdx.x >= blkA);
  int bid = isB ? (int)blockIdx.x - blkA : (int)blockIdx.x;
  const short* xsrc = isB ? xsrcB : xsrcA;
  const short* xdst = isB ? xdstB : xdstA;
  const int* off = isB ? offB : offA;
  const int* col = isB ? colB : colA;
  const float* Wl = isB ? WlB : WlA;
  const float* bl = isB ? blB : blA;
  const float* Wr = isB ? WrB : WrA;
  short* out = isB ? outB : outA;
  int n_dst = isB ? nB : nA;

  int t = threadIdx.x;
  int wave = t >> 6, lane = t & 63;
  int g = lane >> 4, c = lane & 15;

  short8 bw[4][4];
#pragma unroll
  for (int kt = 0; kt < 4; ++kt) {
    const float* Wsrc = (kt < 2) ? Wl : Wr;
    int kbase = (kt & 1) * 32 + 8 * g;
#pragma unroll
    for (int n = 0; n < 4; ++n) {
      short8 w;
#pragma unroll
      for (int j = 0; j < 8; ++j)
        w[j] = f2bf(Wsrc[(kbase + j) * H + 16 * n + c]);
      bw[kt][n] = w;
    }
  }
  float blv[4];
#pragma unroll
  for (int n = 0; n < 4; ++n) blv[n] = bl[16 * n + c];

  int node0 = (bid * 4 + wave) * 16;
  if (node0 >= n_dst) return;

  int mynode = node0 + c;
  int nd = (mynode < n_dst) ? mynode : 0;

  float m[16];
#pragma unroll
  for (int i = 0; i < 16; ++i) m[i] = 0.f;
  int beg = off[nd], end = off[nd + 1];
  int n_nb = end - beg;
  if (n_nb > 0) {
    int idx_c = col[beg];
    int idx_n = (n_nb > 1) ? col[beg + 1] : 0;
    const short8* pc = (const short8*)(xsrc + (size_t)idx_c * H + 8 * g);
    short8 u0 = pc[0], u1 = pc[4];
    for (int j = 1; j < n_nb; ++j) {
      int idx_n2 = (j + 1 < n_nb) ? col[beg + j + 1] : 0;
      const short8* pn = (const short8*)(xsrc + (size_t)idx_n * H + 8 * g);
      short8 v0 = pn[0], v1 = pn[4];
#pragma unroll
      for (int i = 0; i < 8; ++i) {
        m[i] += bf2f(u0[i]);
        m[8 + i] += bf2f(u1[i]);
      }
      u0 = v0;
      u1 = v1;
      idx_n = idx_n2;
    }
#pragma unroll
    for (int i = 0; i < 8; ++i) {
      m[i] += bf2f(u0[i]);
      m[8 + i] += bf2f(u1[i]);
    }
  }
  float invd = (n_nb > 0) ? 1.f / (float)n_nb : 1.f;
  f32x4 m0, m1, m2, m3;
#pragma unroll
  for (int i = 0; i < 4; ++i) {
    m0[i] = m[i] * invd;
    m1[i] = m[4 + i] * invd;
    m2[i] = m[8 + i] * invd;
    m3[i] = m[12 + i] * invd;
  }
  const short8* pr = (const short8*)(xdst + (size_t)nd * H + 8 * g);

  short8 af[4];
  af[0] = cvt8(m0, m1);
  af[1] = cvt8(m2, m3);
  af[2] = pr[0];
  af[3] = pr[4];

  f32x4 zero4 = {0.f, 0.f, 0.f, 0.f};
  f32x4 acc[4];
#pragma unroll
  for (int n = 0; n < 4; ++n) acc[n] = zero4;
#pragma unroll
  for (int kt = 0; kt < 4; ++kt)
#pragma unroll
    for (int n = 0; n < 4; ++n)
      acc[n] = __builtin_amdgcn_mfma_f32_16x16x32_bf16(af[kt], bw[kt][n], acc[n], 0, 0, 0);

#pragma unroll
  for (int n = 0; n < 4; ++n)
#pragma unroll
    for (int r = 0; r < 4; ++r) {
      float o = acc[n][r] + blv[n];
      if (RELU) o = fmaxf(o, 0.f);
      int row = node0 + 4 * g + r;
      if (row < n_dst) out[(size_t)row * H + 16 * n + c] = f2bf(o);
    }
}

// ---------------- edge classifier via MFMA (bf16 gathers) --------------
__global__ __launch_bounds__(256) void edge_mlp_mfma_kernel(
    const short* __restrict__ mch2, const short* __restrict__ mft2,
    const int* __restrict__ src, const int* __restrict__ dst,
    const float* __restrict__ W1, const float* __restrict__ b1,
    const float* __restrict__ W2, const float* __restrict__ b2,
    float* __restrict__ out, int E) {
  int t = threadIdx.x;
  int wave = t >> 6, lane = t & 63;
  int g = lane >> 4, c = lane & 15;

  short8 bw[4][4];
#pragma unroll
  for (int kt = 0; kt < 4; ++kt) {
#pragma unroll
    for (int n = 0; n < 4; ++n) {
      short8 w;
#pragma unroll
      for (int j = 0; j < 8; ++j)
        w[j] = f2bf(W1[(32 * kt + 8 * g + j) * H + 16 * n + c]);
      bw[kt][n] = w;
    }
  }
  float b1v[4], w2v[4];
#pragma unroll
  for (int n = 0; n < 4; ++n) { b1v[n] = b1[16 * n + c]; w2v[n] = W2[16 * n + c]; }
  float b2v = b2[0];
  f32x4 zero4 = {0.f, 0.f, 0.f, 0.f};

  int ntiles = (E + 15) >> 4;
  for (int tile = blockIdx.x * 4 + wave; tile < ntiles; tile += gridDim.x * 4) {
    int e0 = tile * 16;
    int e = e0 + c;
    int ee = (e < E) ? e : E - 1;
    int s = src[ee], d = dst[ee];
    const short8* pa = (const short8*)(mch2 + (size_t)s * H + 8 * g);
    const short8* pb = (const short8*)(mft2 + (size_t)d * H + 8 * g);
    short8 af[4];
    af[0] = pa[0];
    af[1] = pa[4];
    af[2] = pb[0];
    af[3] = pb[4];

    f32x4 acc[4];
#pragma unroll
    for (int n = 0; n < 4; ++n) acc[n] = zero4;
#pragma unroll
    for (int kt = 0; kt < 4; ++kt)
#pragma unroll
      for (int n = 0; n < 4; ++n)
        acc[n] = __builtin_amdgcn_mfma_f32_16x16x32_bf16(af[kt], bw[kt][n], acc[n], 0, 0, 0);

    float part[4];
#pragma unroll
    for (int r = 0; r < 4; ++r) {
      float sum = 0.f;
#pragma unroll
      for (int n = 0; n < 4; ++n) {
        float v = acc[n][r] + b1v[n];
        v = fmaxf(v, 0.f);
        sum = fmaf(v, w2v[n], sum);
      }
      part[r] = sum;
    }
#pragma unroll
    for (int r = 0; r < 4; ++r) {
      part[r] += __shfl_xor(part[r], 1);
      part[r] += __shfl_xor(part[r], 2);
      part[r] += __shfl_xor(part[r], 4);
      part[r] += __shfl_xor(part[r], 8);
    }
    if (c < 4) {
      int eo = e0 + 4 * g + c;
      float v = (c == 0) ? part[0] : (c == 1) ? part[1] : (c == 2) ? part[2] : part[3];
      if (eo < E) out[eo] = 1.f / (1.f + expf(-(v + b2v)));
    }
  }
}

extern "C" void kernel_launch(void* const* d_in, const int* in_sizes, int n_in,
                              void* d_out, int out_size, void* d_ws, size_t ws_size,
                              hipStream_t stream) {
  const float* x_mch = (const float*)d_in[0];
  const float* x_mft = (const float*)d_in[1];
  const int* eidx = (const int*)d_in[2];
  const int E = in_sizes[2] / 2;
  const int* src = eidx;
  const int* dst = eidx + E;
  const float* W_mch = (const float*)d_in[3];
  const float* b_mch = (const float*)d_in[4];
  const float* W_mft = (const float*)d_in[5];
  const float* b_mft = (const float*)d_in[6];
  const float* c1m_Wl = (const float*)d_in[7];
  const float* c1m_bl = (const float*)d_in[8];
  const float* c1m_Wr = (const float*)d_in[9];
  const float* c1r_Wl = (const float*)d_in[10];
  const float* c1r_bl = (const float*)d_in[11];
  const float* c1r_Wr = (const float*)d_in[12];
  const float* c2m_Wl = (const float*)d_in[13];
  const float* c2m_bl = (const float*)d_in[14];
  const float* c2m_Wr = (const float*)d_in[15];
  const float* c2r_Wl = (const float*)d_in[16];
  const float* c2r_bl = (const float*)d_in[17];
  const float* c2r_Wr = (const float*)d_in[18];
  const float* ec_W1 = (const float*)d_in[19];
  const float* ec_b1 = (const float*)d_in[20];
  const float* ec_W2 = (const float*)d_in[21];
  const float* ec_b2 = (const float*)d_in[22];

  const int n_mch = in_sizes[0] / D_IN;
  const int n_mft = in_sizes[1] / D_IN;

  // ---- workspace layout ----
  char* ws = (char*)d_ws;
  auto alloc = [&](size_t bytes) {
    char* p = ws;
    ws += (bytes + 255) & ~(size_t)255;
    return p;
  };
  short* h_mch = (short*)alloc((size_t)n_mch * H * 2);
  short* h_mft = (short*)alloc((size_t)n_mft * H * 2);
  short* mch1 = (short*)alloc((size_t)n_mch * H * 2);
  short* mft1 = (short*)alloc((size_t)n_mft * H * 2);
  short* mch2 = (short*)alloc((size_t)n_mch * H * 2);
  short* mft2 = (short*)alloc((size_t)n_mft * H * 2);
  int* off_mch = (int*)alloc(((size_t)n_mch + 1) * 4);
  int* off_mft = (int*)alloc(((size_t)n_mft + 1) * 4);
  int* cur = (int*)alloc(((size_t)n_mch + n_mft) * 4);
  int* cur_mch = cur;
  int* cur_mft = cur + n_mch;
  int* col_mch = (int*)alloc((size_t)E * 4);
  int* col_mft = (int*)alloc((size_t)E * 4);
  const int nb_mch = (n_mch + 1023) / 1024;
  const int nb_mft = (n_mft + 1023) / 1024;
  int* bsum = (int*)alloc(((size_t)nb_mch + nb_mft) * 4);

  float* out = (float*)d_out;

  // ---- CSR build v3 (XCD-partitioned) ----
  hipMemsetAsync(cur, 0, ((size_t)n_mch + n_mft) * 4, stream);
  degree_part_kernel<<<2048, 256, 0, stream>>>(src, dst, cur_mch, cur_mft, E);
  block_sum_kernel<<<nb_mch + nb_mft, 256, 0, stream>>>(cur_mch, n_mch, cur_mft, n_mft,
                                                        bsum, nb_mch);
  bsum_scan_kernel<<<2, 512, 0, stream>>>(bsum, nb_mch, nb_mft);
  scan_write_kernel<<<nb_mch + nb_mft, 256, 0, stream>>>(
      cur_mch, off_mch, cur_mch, n_mch, cur_mft, off_mft, cur_mft, n_mft, bsum, nb_mch, E);
  fill_part_kernel<<<2048, 256, 0, stream>>>(src, dst, cur_mch, cur_mft,
                                             col_mch, col_mft, E);

  // ---- input projections ----
  {
    int blk = ((n_mch * H) + 255) / 256;
    proj_kernel<<<blk, 256, 0, stream>>>(x_mch, W_mch, b_mch, h_mch, n_mch);
    blk = ((n_mft * H) + 255) / 256;
    proj_kernel<<<blk, 256, 0, stream>>>(x_mft, W_mft, b_mft, h_mft, n_mft);
  }

  // ---- convs (MFMA, both directions per launch) ----
  {
    int tiles_mft = (n_mft + 15) / 16;
    int tiles_mch = (n_mch + 15) / 16;
    int blkA = (tiles_mft + 3) / 4;
    int blkB = (tiles_mch + 3) / 4;
    sage_dual_kernel<true><<<blkA + blkB, 256, 0, stream>>>(
        h_mch, h_mft, off_mft, col_mft, c1m_Wl, c1m_bl, c1m_Wr, mft1, n_mft, blkA,
        h_mft, h_mch, off_mch, col_mch, c1r_Wl, c1r_bl, c1r_Wr, mch1, n_mch);
    sage_dual_kernel<false><<<blkA + blkB, 256, 0, stream>>>(
        mch1, mft1, off_mft, col_mft, c2m_Wl, c2m_bl, c2m_Wr, mft2, n_mft, blkA,
        mft1, mch1, off_mch, col_mch, c2r_Wl, c2r_bl, c2r_Wr, mch2, n_mch);
  }

  // ---- edge classifier (MFMA) ----
  {
    edge_mlp_mfma_kernel<<<2048, 256, 0, stream>>>(mch2, mft2, src, dst,
                                                   ec_W1, ec_b1, ec_W2, ec_b2, out, E);
  }
}

// Round 7
// 386.872 us; speedup vs baseline: 1.3452x; 1.1195x over previous
//
#include <hip/hip_runtime.h>
#include <math.h>

#define D_IN 5
#define H 64
#define PART_SHIFT 4  // partition = (node >> 4) & 7 : 16-node groups -> one 64B cur line per partition

using f32x4 = __attribute__((ext_vector_type(4))) float;
using short8 = __attribute__((ext_vector_type(8))) short;

__device__ inline short f2bf(float f) {
  unsigned u = __builtin_bit_cast(unsigned, f);
  u += 0x7fffu + ((u >> 16) & 1u);  // round-to-nearest-even
  return (short)(u >> 16);
}
__device__ inline float bf2f(short s) {
  return __builtin_bit_cast(float, ((unsigned)(unsigned short)s) << 16);
}
__device__ inline short8 cvt8(f32x4 a, f32x4 b) {
  short8 r;
  r[0] = f2bf(a[0]); r[1] = f2bf(a[1]); r[2] = f2bf(a[2]); r[3] = f2bf(a[3]);
  r[4] = f2bf(b[0]); r[5] = f2bf(b[1]); r[6] = f2bf(b[2]); r[7] = f2bf(b[3]);
  return r;
}
__device__ inline void acc16(float* m, const short8& a, const short8& b) {
#pragma unroll
  for (int i = 0; i < 8; ++i) {
    m[i] += bf2f(a[i]);
    m[8 + i] += bf2f(b[i]);
  }
}

// ---------------- input projection ----------------
__global__ __launch_bounds__(256) void proj_kernel(
    const float* __restrict__ x, const float* __restrict__ W,
    const float* __restrict__ b, short* __restrict__ out, int n) {
  __shared__ float Ws[D_IN * H];
  __shared__ float bs[H];
  int t = threadIdx.x;
  for (int i = t; i < D_IN * H; i += 256) Ws[i] = W[i];
  if (t < H) bs[t] = b[t];
  __syncthreads();
  int idx = blockIdx.x * 256 + t;
  int node = idx >> 6;
  int h = idx & 63;
  if (node >= n) return;
  const float* xr = x + (size_t)node * D_IN;
  float acc = bs[h];
#pragma unroll
  for (int d = 0; d < D_IN; ++d) acc = fmaf(xr[d], Ws[d * H + h], acc);
  out[(size_t)node * H + h] = f2bf(acc);
}

// ---------------- CSR build v3: XCD-partitioned degree + fill ----------------
__global__ __launch_bounds__(256) void degree_part_kernel(
    const int* __restrict__ src, const int* __restrict__ dst,
    int* cur_mch, int* cur_mft, int E) {
  int cohort = blockIdx.x & 7;
  int w = blockIdx.x >> 3;
  int nw = gridDim.x >> 3;
  int stride = nw * 256 * 4;
  for (int e0 = (w * 256 + (int)threadIdx.x) * 4; e0 < E; e0 += stride) {
    if (e0 + 4 <= E) {
      int4 s4 = *(const int4*)(src + e0);
      int4 d4 = *(const int4*)(dst + e0);
      if (((s4.x >> PART_SHIFT) & 7) == cohort) atomicAdd(&cur_mch[s4.x], 1);
      if (((s4.y >> PART_SHIFT) & 7) == cohort) atomicAdd(&cur_mch[s4.y], 1);
      if (((s4.z >> PART_SHIFT) & 7) == cohort) atomicAdd(&cur_mch[s4.z], 1);
      if (((s4.w >> PART_SHIFT) & 7) == cohort) atomicAdd(&cur_mch[s4.w], 1);
      if (((d4.x >> PART_SHIFT) & 7) == cohort) atomicAdd(&cur_mft[d4.x], 1);
      if (((d4.y >> PART_SHIFT) & 7) == cohort) atomicAdd(&cur_mft[d4.y], 1);
      if (((d4.z >> PART_SHIFT) & 7) == cohort) atomicAdd(&cur_mft[d4.z], 1);
      if (((d4.w >> PART_SHIFT) & 7) == cohort) atomicAdd(&cur_mft[d4.w], 1);
    } else {
      for (int i = 0; i < 4; ++i) {
        int e = e0 + i;
        if (e < E) {
          int s = src[e], d = dst[e];
          if (((s >> PART_SHIFT) & 7) == cohort) atomicAdd(&cur_mch[s], 1);
          if (((d >> PART_SHIFT) & 7) == cohort) atomicAdd(&cur_mft[d], 1);
        }
      }
    }
  }
}

__global__ __launch_bounds__(256) void block_sum_kernel(
    const int* __restrict__ deg0, int n0,
    const int* __restrict__ deg1, int n1,
    int* __restrict__ bsum, int nb0) {
  int b = blockIdx.x;
  bool a1 = (b >= nb0);
  const int* deg = a1 ? deg1 : deg0;
  int n = a1 ? n1 : n0;
  int base = (a1 ? b - nb0 : b) * 1024;
  int t = threadIdx.x;
  int s = 0;
#pragma unroll
  for (int i = 0; i < 4; ++i) {
    int idx = base + t * 4 + i;
    if (idx < n) s += deg[idx];
  }
  __shared__ int red[256];
  red[t] = s;
  __syncthreads();
  for (int st = 128; st; st >>= 1) {
    if (t < st) red[t] += red[t + st];
    __syncthreads();
  }
  if (t == 0) bsum[b] = red[0];
}

__global__ __launch_bounds__(512) void bsum_scan_kernel(int* bsum, int nb0, int nb1) {
  int lo = blockIdx.x ? nb0 : 0;
  int nb = blockIdx.x ? nb1 : nb0;
  __shared__ int tmp[512];
  int t = threadIdx.x;
  int v = (t < nb) ? bsum[lo + t] : 0;
  tmp[t] = v;
  __syncthreads();
  for (int s = 1; s < 512; s <<= 1) {
    int add = (t >= s) ? tmp[t - s] : 0;
    __syncthreads();
    tmp[t] += add;
    __syncthreads();
  }
  if (t < nb) bsum[lo + t] = tmp[t] - v;  // exclusive
}

__global__ __launch_bounds__(256) void scan_write_kernel(
    const int* __restrict__ deg0, int* __restrict__ off0, int* __restrict__ cur0, int n0,
    const int* __restrict__ deg1, int* __restrict__ off1, int* __restrict__ cur1, int n1,
    const int* __restrict__ bsum, int nb0, int E) {
  int b = blockIdx.x;
  bool a1 = (b >= nb0);
  const int* deg = a1 ? deg1 : deg0;
  int* off = a1 ? off1 : off0;
  int* cur = a1 ? cur1 : cur0;
  int n = a1 ? n1 : n0;
  int base = (a1 ? b - nb0 : b) * 1024;
  int t = threadIdx.x;
  int v[4];
  int s = 0;
#pragma unroll
  for (int i = 0; i < 4; ++i) {
    int idx = base + t * 4 + i;
    v[i] = (idx < n) ? deg[idx] : 0;
    s += v[i];
  }
  __shared__ int tmp[256];
  tmp[t] = s;
  __syncthreads();
  for (int st = 1; st < 256; st <<= 1) {
    int add = (t >= st) ? tmp[t - st] : 0;
    __syncthreads();
    tmp[t] += add;
    __syncthreads();
  }
  int run = bsum[b] + tmp[t] - s;
#pragma unroll
  for (int i = 0; i < 4; ++i) {
    int idx = base + t * 4 + i;
    if (idx < n) {
      off[idx] = run;
      cur[idx] = run;
      run += v[i];
      if (idx == n - 1) off[n] = E;
    }
  }
}

__global__ __launch_bounds__(256) void fill_part_kernel(
    const int* __restrict__ src, const int* __restrict__ dst,
    int* cur_mch, int* cur_mft,
    int* __restrict__ col_mch, int* __restrict__ col_mft, int E) {
  int cohort = blockIdx.x & 7;
  int w = blockIdx.x >> 3;
  int nw = gridDim.x >> 3;
  int stride = nw * 256 * 4;
  for (int e0 = (w * 256 + (int)threadIdx.x) * 4; e0 < E; e0 += stride) {
    if (e0 + 4 <= E) {
      int4 s4 = *(const int4*)(src + e0);
      int4 d4 = *(const int4*)(dst + e0);
      if (((d4.x >> PART_SHIFT) & 7) == cohort) col_mft[atomicAdd(&cur_mft[d4.x], 1)] = s4.x;
      if (((d4.y >> PART_SHIFT) & 7) == cohort) col_mft[atomicAdd(&cur_mft[d4.y], 1)] = s4.y;
      if (((d4.z >> PART_SHIFT) & 7) == cohort) col_mft[atomicAdd(&cur_mft[d4.z], 1)] = s4.z;
      if (((d4.w >> PART_SHIFT) & 7) == cohort) col_mft[atomicAdd(&cur_mft[d4.w], 1)] = s4.w;
      if (((s4.x >> PART_SHIFT) & 7) == cohort) col_mch[atomicAdd(&cur_mch[s4.x], 1)] = d4.x;
      if (((s4.y >> PART_SHIFT) & 7) == cohort) col_mch[atomicAdd(&cur_mch[s4.y], 1)] = d4.y;
      if (((s4.z >> PART_SHIFT) & 7) == cohort) col_mch[atomicAdd(&cur_mch[s4.z], 1)] = d4.z;
      if (((s4.w >> PART_SHIFT) & 7) == cohort) col_mch[atomicAdd(&cur_mch[s4.w], 1)] = d4.w;
    } else {
      for (int i = 0; i < 4; ++i) {
        int e = e0 + i;
        if (e < E) {
          int s = src[e], d = dst[e];
          if (((d >> PART_SHIFT) & 7) == cohort) col_mft[atomicAdd(&cur_mft[d], 1)] = s;
          if (((s >> PART_SHIFT) & 7) == cohort) col_mch[atomicAdd(&cur_mch[s], 1)] = d;
        }
      }
    }
  }
}

// ---------------- fused SAGE via MFMA, LDS weights + 4-burst gather ----------------
template <bool RELU>
__global__ __launch_bounds__(256) void sage_dual_kernel(
    const short* __restrict__ xsrcA, const short* __restrict__ xdstA,
    const int* __restrict__ offA, const int* __restrict__ colA,
    const float* __restrict__ WlA, const float* __restrict__ blA,
    const float* __restrict__ WrA, short* __restrict__ outA, int nA, int blkA,
    const short* __restrict__ xsrcB, const short* __restrict__ xdstB,
    const int* __restrict__ offB, const int* __restrict__ colB,
    const float* __restrict__ WlB, const float* __restrict__ blB,
    const float* __restrict__ WrB, short* __restrict__ outB, int nB) {
  bool isB = ((int)blockIdx.x >= blkA);
  int bid = isB ? (int)blockIdx.x - blkA : (int)blockIdx.x;
  const short* xsrc = isB ? xsrcB : xsrcA;
  const short* xdst = isB ? xdstB : xdstA;
  const int* off = isB ? offB : offA;
  const int* col = isB ? colB : colA;
  const float* Wl = isB ? WlB : WlA;
  const float* bl = isB ? blB : blA;
  const float* Wr = isB ? WrB : WrA;
  short* out = isB ? outB : outA;
  int n_dst = isB ? nB : nA;

  int t = threadIdx.x;
  int wave = t >> 6, lane = t & 63;
  int g = lane >> 4, c = lane & 15;

  // B fragments in LDS: lds_bw[kt][n][lane], built cooperatively once per block.
  __shared__ short8 lds_bw[4][4][64];
  for (int i = t; i < 4 * 4 * 64; i += 256) {
    int kt = i >> 8;
    int nn = (i >> 6) & 3;
    int ln = i & 63;
    int gg = ln >> 4, cc = ln & 15;
    const float* Wsrc = (kt < 2) ? Wl : Wr;
    int kbase = (kt & 1) * 32 + 8 * gg;
    short8 w;
#pragma unroll
    for (int j = 0; j < 8; ++j)
      w[j] = f2bf(Wsrc[(kbase + j) * H + 16 * nn + cc]);
    lds_bw[kt][nn][ln] = w;
  }
  __syncthreads();

  int node0 = (bid * 4 + wave) * 16;
  if (node0 >= n_dst) return;

  int mynode = node0 + c;
  int nd = (mynode < n_dst) ? mynode : 0;

  float blv[4];
#pragma unroll
  for (int n = 0; n < 4; ++n) blv[n] = bl[16 * n + c];

  // hoist root-row loads (independent of neighbor loop)
  const short8* pr = (const short8*)(xdst + (size_t)nd * H + 8 * g);
  short8 r0 = pr[0], r1 = pr[4];

  // mean-aggregate: 4-burst batched loads for deep MLP
  float m[16];
#pragma unroll
  for (int i = 0; i < 16; ++i) m[i] = 0.f;
  int beg = off[nd];
  int n_nb = off[nd + 1] - beg;
  for (int jb = 0; jb < n_nb; jb += 4) {
    int rem = n_nb - jb;
    int j1 = jb + (rem > 1 ? 1 : 0);
    int j2 = jb + (rem > 2 ? 2 : 0);
    int j3 = jb + (rem > 3 ? 3 : 0);
    int i0 = col[beg + jb];
    int i1 = col[beg + j1];
    int i2 = col[beg + j2];
    int i3 = col[beg + j3];
    const short8* p0 = (const short8*)(xsrc + (size_t)i0 * H + 8 * g);
    const short8* p1 = (const short8*)(xsrc + (size_t)i1 * H + 8 * g);
    const short8* p2 = (const short8*)(xsrc + (size_t)i2 * H + 8 * g);
    const short8* p3 = (const short8*)(xsrc + (size_t)i3 * H + 8 * g);
    short8 a0 = p0[0], b0 = p0[4];
    short8 a1 = p1[0], b1 = p1[4];
    short8 a2 = p2[0], b2 = p2[4];
    short8 a3 = p3[0], b3 = p3[4];
    acc16(m, a0, b0);
    if (rem > 1) acc16(m, a1, b1);
    if (rem > 2) acc16(m, a2, b2);
    if (rem > 3) acc16(m, a3, b3);
  }
  float invd = (n_nb > 0) ? 1.f / (float)n_nb : 1.f;
  f32x4 m0, m1, m2, m3;
#pragma unroll
  for (int i = 0; i < 4; ++i) {
    m0[i] = m[i] * invd;
    m1[i] = m[4 + i] * invd;
    m2[i] = m[8 + i] * invd;
    m3[i] = m[12 + i] * invd;
  }

  short8 af[4];
  af[0] = cvt8(m0, m1);
  af[1] = cvt8(m2, m3);
  af[2] = r0;
  af[3] = r1;

  f32x4 zero4 = {0.f, 0.f, 0.f, 0.f};
  f32x4 acc[4];
#pragma unroll
  for (int n = 0; n < 4; ++n) acc[n] = zero4;
#pragma unroll
  for (int kt = 0; kt < 4; ++kt)
#pragma unroll
    for (int n = 0; n < 4; ++n)
      acc[n] = __builtin_amdgcn_mfma_f32_16x16x32_bf16(af[kt], lds_bw[kt][n][lane], acc[n], 0, 0, 0);

#pragma unroll
  for (int n = 0; n < 4; ++n)
#pragma unroll
    for (int r = 0; r < 4; ++r) {
      float o = acc[n][r] + blv[n];
      if (RELU) o = fmaxf(o, 0.f);
      int row = node0 + 4 * g + r;
      if (row < n_dst) out[(size_t)row * H + 16 * n + c] = f2bf(o);
    }
}

// ---------------- edge classifier via MFMA, LDS weights + 2-deep tile pipeline --------
__global__ __launch_bounds__(256) void edge_mlp_mfma_kernel(
    const short* __restrict__ mch2, const short* __restrict__ mft2,
    const int* __restrict__ src, const int* __restrict__ dst,
    const float* __restrict__ W1, const float* __restrict__ b1,
    const float* __restrict__ W2, const float* __restrict__ b2,
    float* __restrict__ out, int E) {
  int t = threadIdx.x;
  int wave = t >> 6, lane = t & 63;
  int g = lane >> 4, c = lane & 15;

  __shared__ short8 lds_bw[4][4][64];
  for (int i = t; i < 4 * 4 * 64; i += 256) {
    int kt = i >> 8;
    int nn = (i >> 6) & 3;
    int ln = i & 63;
    int gg = ln >> 4, cc = ln & 15;
    int kbase = 32 * kt + 8 * gg;
    short8 w;
#pragma unroll
    for (int j = 0; j < 8; ++j)
      w[j] = f2bf(W1[(kbase + j) * H + 16 * nn + cc]);
    lds_bw[kt][nn][ln] = w;
  }
  __syncthreads();

  float b1v[4], w2v[4];
#pragma unroll
  for (int n = 0; n < 4; ++n) { b1v[n] = b1[16 * n + c]; w2v[n] = W2[16 * n + c]; }
  float b2v = b2[0];
  f32x4 zero4 = {0.f, 0.f, 0.f, 0.f};

  int ntiles = (E + 15) >> 4;
  int stride = gridDim.x * 4;
  int t0 = blockIdx.x * 4 + wave;
  if (t0 >= ntiles) return;

  auto loadIdx = [&](int tile, int& s, int& d) {
    int e = tile * 16 + c;
    int ee = (e < E) ? e : E - 1;
    s = src[ee];
    d = dst[ee];
  };
  auto loadRows = [&](int s, int d, short8* af) {
    const short8* pa = (const short8*)(mch2 + (size_t)s * H + 8 * g);
    const short8* pb = (const short8*)(mft2 + (size_t)d * H + 8 * g);
    af[0] = pa[0];
    af[1] = pa[4];
    af[2] = pb[0];
    af[3] = pb[4];
  };

  int sA, dA, sB, dB;
  short8 afA[4];
  loadIdx(t0, sA, dA);
  loadRows(sA, dA, afA);
  {
    int tB = t0 + stride;
    loadIdx((tB < ntiles) ? tB : (ntiles - 1), sB, dB);
  }

  for (int tile = t0; tile < ntiles; tile += stride) {
    // prefetch next tile's rows + next-next indices
    short8 afB[4];
    loadRows(sB, dB, afB);
    int sC, dC;
    {
      int tC = tile + 2 * stride;
      loadIdx((tC < ntiles) ? tC : (ntiles - 1), sC, dC);
    }

    f32x4 acc[4];
#pragma unroll
    for (int n = 0; n < 4; ++n) acc[n] = zero4;
#pragma unroll
    for (int kt = 0; kt < 4; ++kt)
#pragma unroll
      for (int n = 0; n < 4; ++n)
        acc[n] = __builtin_amdgcn_mfma_f32_16x16x32_bf16(afA[kt], lds_bw[kt][n][lane], acc[n], 0, 0, 0);

    float part[4];
#pragma unroll
    for (int r = 0; r < 4; ++r) {
      float sum = 0.f;
#pragma unroll
      for (int n = 0; n < 4; ++n) {
        float v = acc[n][r] + b1v[n];
        v = fmaxf(v, 0.f);
        sum = fmaf(v, w2v[n], sum);
      }
      part[r] = sum;
    }
#pragma unroll
    for (int r = 0; r < 4; ++r) {
      part[r] += __shfl_xor(part[r], 1);
      part[r] += __shfl_xor(part[r], 2);
      part[r] += __shfl_xor(part[r], 4);
      part[r] += __shfl_xor(part[r], 8);
    }
    if (c < 4) {
      int eo = tile * 16 + 4 * g + c;
      float v = (c == 0) ? part[0] : (c == 1) ? part[1] : (c == 2) ? part[2] : part[3];
      if (eo < E) out[eo] = 1.f / (1.f + expf(-(v + b2v)));
    }

    // rotate pipeline
#pragma unroll
    for (int i = 0; i < 4; ++i) afA[i] = afB[i];
    sB = sC;
    dB = dC;
  }
}

extern "C" void kernel_launch(void* const* d_in, const int* in_sizes, int n_in,
                              void* d_out, int out_size, void* d_ws, size_t ws_size,
                              hipStream_t stream) {
  const float* x_mch = (const float*)d_in[0];
  const float* x_mft = (const float*)d_in[1];
  const int* eidx = (const int*)d_in[2];
  const int E = in_sizes[2] / 2;
  const int* src = eidx;
  const int* dst = eidx + E;
  const float* W_mch = (const float*)d_in[3];
  const float* b_mch = (const float*)d_in[4];
  const float* W_mft = (const float*)d_in[5];
  const float* b_mft = (const float*)d_in[6];
  const float* c1m_Wl = (const float*)d_in[7];
  const float* c1m_bl = (const float*)d_in[8];
  const float* c1m_Wr = (const float*)d_in[9];
  const float* c1r_Wl = (const float*)d_in[10];
  const float* c1r_bl = (const float*)d_in[11];
  const float* c1r_Wr = (const float*)d_in[12];
  const float* c2m_Wl = (const float*)d_in[13];
  const float* c2m_bl = (const float*)d_in[14];
  const float* c2m_Wr = (const float*)d_in[15];
  const float* c2r_Wl = (const float*)d_in[16];
  const float* c2r_bl = (const float*)d_in[17];
  const float* c2r_Wr = (const float*)d_in[18];
  const float* ec_W1 = (const float*)d_in[19];
  const float* ec_b1 = (const float*)d_in[20];
  const float* ec_W2 = (const float*)d_in[21];
  const float* ec_b2 = (const float*)d_in[22];

  const int n_mch = in_sizes[0] / D_IN;
  const int n_mft = in_sizes[1] / D_IN;

  // ---- workspace layout ----
  char* ws = (char*)d_ws;
  auto alloc = [&](size_t bytes) {
    char* p = ws;
    ws += (bytes + 255) & ~(size_t)255;
    return p;
  };
  short* h_mch = (short*)alloc((size_t)n_mch * H * 2);
  short* h_mft = (short*)alloc((size_t)n_mft * H * 2);
  short* mch1 = (short*)alloc((size_t)n_mch * H * 2);
  short* mft1 = (short*)alloc((size_t)n_mft * H * 2);
  short* mch2 = (short*)alloc((size_t)n_mch * H * 2);
  short* mft2 = (short*)alloc((size_t)n_mft * H * 2);
  int* off_mch = (int*)alloc(((size_t)n_mch + 1) * 4);
  int* off_mft = (int*)alloc(((size_t)n_mft + 1) * 4);
  int* cur = (int*)alloc(((size_t)n_mch + n_mft) * 4);
  int* cur_mch = cur;
  int* cur_mft = cur + n_mch;
  int* col_mch = (int*)alloc((size_t)E * 4);
  int* col_mft = (int*)alloc((size_t)E * 4);
  const int nb_mch = (n_mch + 1023) / 1024;
  const int nb_mft = (n_mft + 1023) / 1024;
  int* bsum = (int*)alloc(((size_t)nb_mch + nb_mft) * 4);

  float* out = (float*)d_out;

  // ---- CSR build v3 (XCD-partitioned) ----
  hipMemsetAsync(cur, 0, ((size_t)n_mch + n_mft) * 4, stream);
  degree_part_kernel<<<2048, 256, 0, stream>>>(src, dst, cur_mch, cur_mft, E);
  block_sum_kernel<<<nb_mch + nb_mft, 256, 0, stream>>>(cur_mch, n_mch, cur_mft, n_mft,
                                                        bsum, nb_mch);
  bsum_scan_kernel<<<2, 512, 0, stream>>>(bsum, nb_mch, nb_mft);
  scan_write_kernel<<<nb_mch + nb_mft, 256, 0, stream>>>(
      cur_mch, off_mch, cur_mch, n_mch, cur_mft, off_mft, cur_mft, n_mft, bsum, nb_mch, E);
  fill_part_kernel<<<2048, 256, 0, stream>>>(src, dst, cur_mch, cur_mft,
                                             col_mch, col_mft, E);

  // ---- input projections ----
  {
    int blk = ((n_mch * H) + 255) / 256;
    proj_kernel<<<blk, 256, 0, stream>>>(x_mch, W_mch, b_mch, h_mch, n_mch);
    blk = ((n_mft * H) + 255) / 256;
    proj_kernel<<<blk, 256, 0, stream>>>(x_mft, W_mft, b_mft, h_mft, n_mft);
  }

  // ---- convs (MFMA, both directions per launch) ----
  {
    int tiles_mft = (n_mft + 15) / 16;
    int tiles_mch = (n_mch + 15) / 16;
    int blkA = (tiles_mft + 3) / 4;
    int blkB = (tiles_mch + 3) / 4;
    sage_dual_kernel<true><<<blkA + blkB, 256, 0, stream>>>(
        h_mch, h_mft, off_mft, col_mft, c1m_Wl, c1m_bl, c1m_Wr, mft1, n_mft, blkA,
        h_mft, h_mch, off_mch, col_mch, c1r_Wl, c1r_bl, c1r_Wr, mch1, n_mch);
    sage_dual_kernel<false><<<blkA + blkB, 256, 0, stream>>>(
        mch1, mft1, off_mft, col_mft, c2m_Wl, c2m_bl, c2m_Wr, mft2, n_mft, blkA,
        mft1, mch1, off_mch, col_mch, c2r_Wl, c2r_bl, c2r_Wr, mch2, n_mch);
  }

  // ---- edge classifier (MFMA) ----
  {
    edge_mlp_mfma_kernel<<<2048, 256, 0, stream>>>(mch2, mft2, src, dst,
                                                   ec_W1, ec_b1, ec_W2, ec_b2, out, E);
  }
}

// Round 8
// 257.359 us; speedup vs baseline: 2.0221x; 1.5032x over previous
//
#include <hip/hip_runtime.h>
#include <math.h>

#define D_IN 5
#define H 64
#define GSH 8        // 256-node groups
#define MAXG 512     // max groups per side (100k/256 = 391)
#define CHUNK 4096   // edges per block in count/scatter

using f32x4 = __attribute__((ext_vector_type(4))) float;
using short8 = __attribute__((ext_vector_type(8))) short;

__device__ inline short f2bf(float f) {
  unsigned u = __builtin_bit_cast(unsigned, f);
  u += 0x7fffu + ((u >> 16) & 1u);  // round-to-nearest-even
  return (short)(u >> 16);
}
__device__ inline float bf2f(short s) {
  return __builtin_bit_cast(float, ((unsigned)(unsigned short)s) << 16);
}
__device__ inline short8 cvt8(f32x4 a, f32x4 b) {
  short8 r;
  r[0] = f2bf(a[0]); r[1] = f2bf(a[1]); r[2] = f2bf(a[2]); r[3] = f2bf(a[3]);
  r[4] = f2bf(b[0]); r[5] = f2bf(b[1]); r[6] = f2bf(b[2]); r[7] = f2bf(b[3]);
  return r;
}
__device__ inline void acc16(float* m, const short8& a, const short8& b) {
#pragma unroll
  for (int i = 0; i < 8; ++i) {
    m[i] += bf2f(a[i]);
    m[8 + i] += bf2f(b[i]);
  }
}

// ---------------- input projection ----------------
__global__ __launch_bounds__(256) void proj_kernel(
    const float* __restrict__ x, const float* __restrict__ W,
    const float* __restrict__ b, short* __restrict__ out, int n) {
  __shared__ float Ws[D_IN * H];
  __shared__ float bs[H];
  int t = threadIdx.x;
  for (int i = t; i < D_IN * H; i += 256) Ws[i] = W[i];
  if (t < H) bs[t] = b[t];
  __syncthreads();
  int idx = blockIdx.x * 256 + t;
  int node = idx >> 6;
  int h = idx & 63;
  if (node >= n) return;
  const float* xr = x + (size_t)node * D_IN;
  float acc = bs[h];
#pragma unroll
  for (int d = 0; d < D_IN; ++d) acc = fmaf(xr[d], Ws[d * H + h], acc);
  out[(size_t)node * H + h] = f2bf(acc);
}

// ---------------- CSR build v4: block-aggregated two-level counting sort ----------------
// S side: group by src -> col_mch (payload = dst). D side: group by dst -> col_mft (payload = src).

// pass A: per-block LDS group histogram; ONE global atomic per (block,group).
__global__ __launch_bounds__(256) void group_count_kernel(
    const int* __restrict__ src, const int* __restrict__ dst,
    int* __restrict__ gcntS, int* __restrict__ gcntD,
    int* __restrict__ baseS, int* __restrict__ baseD,
    int nGS, int nGD, int E) {
  __shared__ int hS[MAXG], hD[MAXG];
  int t = threadIdx.x;
  int b = blockIdx.x;
  for (int i = t; i < MAXG; i += 256) { hS[i] = 0; hD[i] = 0; }
  __syncthreads();
  int e0 = b * CHUNK;
#pragma unroll
  for (int it = 0; it < CHUNK / 1024; ++it) {
    int e = e0 + (it * 256 + t) * 4;
    if (e + 4 <= E) {
      int4 s4 = *(const int4*)(src + e);
      int4 d4 = *(const int4*)(dst + e);
      atomicAdd(&hS[s4.x >> GSH], 1);
      atomicAdd(&hS[s4.y >> GSH], 1);
      atomicAdd(&hS[s4.z >> GSH], 1);
      atomicAdd(&hS[s4.w >> GSH], 1);
      atomicAdd(&hD[d4.x >> GSH], 1);
      atomicAdd(&hD[d4.y >> GSH], 1);
      atomicAdd(&hD[d4.z >> GSH], 1);
      atomicAdd(&hD[d4.w >> GSH], 1);
    } else {
      for (int i = 0; i < 4; ++i) {
        int ee = e + i;
        if (ee < E) {
          atomicAdd(&hS[src[ee] >> GSH], 1);
          atomicAdd(&hD[dst[ee] >> GSH], 1);
        }
      }
    }
  }
  __syncthreads();
  for (int g = t; g < nGS; g += 256) {
    int h = hS[g];
    baseS[(size_t)b * nGS + g] = h ? atomicAdd(&gcntS[g], h) : 0;
  }
  for (int g = t; g < nGD; g += 256) {
    int h = hD[g];
    baseD[(size_t)b * nGD + g] = h ? atomicAdd(&gcntD[g], h) : 0;
  }
}

// pass B: exclusive scan of group counts (block 0 -> S, block 1 -> D). nG <= 512.
__global__ __launch_bounds__(512) void goff_scan_kernel(
    const int* __restrict__ gcntS, int* __restrict__ GoffS, int nGS,
    const int* __restrict__ gcntD, int* __restrict__ GoffD, int nGD) {
  const int* c = blockIdx.x ? gcntD : gcntS;
  int* G = blockIdx.x ? GoffD : GoffS;
  int n = blockIdx.x ? nGD : nGS;
  __shared__ int tmp[512];
  int t = threadIdx.x;
  int v = (t < n) ? c[t] : 0;
  tmp[t] = v;
  __syncthreads();
  for (int s = 1; s < 512; s <<= 1) {
    int add = (t >= s) ? tmp[t - s] : 0;
    __syncthreads();
    tmp[t] += add;
    __syncthreads();
  }
  if (t < n) G[t] = tmp[t] - v;
  if (t == n - 1) G[n] = tmp[t];
}

// pass C: re-read chunk, LDS cursors = Goff + block base, write (payload,node) pairs
// into block-private runs of the group staging windows. LDS atomics only.
__global__ __launch_bounds__(256) void stage_scatter_kernel(
    const int* __restrict__ src, const int* __restrict__ dst,
    const int* __restrict__ GoffS, const int* __restrict__ GoffD,
    const int* __restrict__ baseS, const int* __restrict__ baseD,
    uint2* __restrict__ stageS, uint2* __restrict__ stageD,
    int nGS, int nGD, int E) {
  __shared__ int cS[MAXG], cD[MAXG];
  int t = threadIdx.x;
  int b = blockIdx.x;
  for (int g = t; g < nGS; g += 256) cS[g] = GoffS[g] + baseS[(size_t)b * nGS + g];
  for (int g = t; g < nGD; g += 256) cD[g] = GoffD[g] + baseD[(size_t)b * nGD + g];
  __syncthreads();
  int e0 = b * CHUNK;
#pragma unroll
  for (int it = 0; it < CHUNK / 1024; ++it) {
    int e = e0 + (it * 256 + t) * 4;
    if (e + 4 <= E) {
      int4 s4 = *(const int4*)(src + e);
      int4 d4 = *(const int4*)(dst + e);
      int pS0 = atomicAdd(&cS[s4.x >> GSH], 1);
      int pS1 = atomicAdd(&cS[s4.y >> GSH], 1);
      int pS2 = atomicAdd(&cS[s4.z >> GSH], 1);
      int pS3 = atomicAdd(&cS[s4.w >> GSH], 1);
      int pD0 = atomicAdd(&cD[d4.x >> GSH], 1);
      int pD1 = atomicAdd(&cD[d4.y >> GSH], 1);
      int pD2 = atomicAdd(&cD[d4.z >> GSH], 1);
      int pD3 = atomicAdd(&cD[d4.w >> GSH], 1);
      stageS[pS0] = make_uint2(d4.x, s4.x);
      stageS[pS1] = make_uint2(d4.y, s4.y);
      stageS[pS2] = make_uint2(d4.z, s4.z);
      stageS[pS3] = make_uint2(d4.w, s4.w);
      stageD[pD0] = make_uint2(s4.x, d4.x);
      stageD[pD1] = make_uint2(s4.y, d4.y);
      stageD[pD2] = make_uint2(s4.z, d4.z);
      stageD[pD3] = make_uint2(s4.w, d4.w);
    } else {
      for (int i = 0; i < 4; ++i) {
        int ee = e + i;
        if (ee < E) {
          int s = src[ee], d = dst[ee];
          int pS = atomicAdd(&cS[s >> GSH], 1);
          int pD = atomicAdd(&cD[d >> GSH], 1);
          stageS[pS] = make_uint2(d, s);
          stageD[pD] = make_uint2(s, d);
        }
      }
    }
  }
}

// pass D: one block per (side,group): node histogram + scan -> off[], then scatter col
// into the group's contiguous window. All atomics in LDS.
__global__ __launch_bounds__(256) void finalize_group_kernel(
    const uint2* __restrict__ stageS, const int* __restrict__ GoffS, int nGS, int n_mch,
    int* __restrict__ off_mch, int* __restrict__ col_mch,
    const uint2* __restrict__ stageD, const int* __restrict__ GoffD, int n_mft,
    int* __restrict__ off_mft, int* __restrict__ col_mft, int E) {
  int b = blockIdx.x;
  const uint2* stage;
  const int* Goff;
  int n, g;
  int* off;
  int* col;
  if (b >= nGS) {
    g = b - nGS;
    stage = stageD; Goff = GoffD; n = n_mft; off = off_mft; col = col_mft;
  } else {
    g = b;
    stage = stageS; Goff = GoffS; n = n_mch; off = off_mch; col = col_mch;
  }
  int base = Goff[g];
  int cnt = Goff[g + 1] - base;
  int t = threadIdx.x;

  __shared__ int tmp[256];
  __shared__ int curs[256];
  tmp[t] = 0;
  __syncthreads();
  for (int j = t; j < cnt; j += 256) {
    uint2 p = stage[base + j];
    atomicAdd(&tmp[p.y & 255], 1);
  }
  __syncthreads();
  int v = tmp[t];
  __syncthreads();
  tmp[t] = v;
  __syncthreads();
  for (int s = 1; s < 256; s <<= 1) {
    int add = (t >= s) ? tmp[t - s] : 0;
    __syncthreads();
    tmp[t] += add;
    __syncthreads();
  }
  int excl = tmp[t] - v;
  int gnode = (g << GSH) + t;
  if (gnode < n) {
    off[gnode] = base + excl;
    if (gnode == n - 1) off[n] = E;
  }
  curs[t] = base + excl;
  __syncthreads();
  for (int j = t; j < cnt; j += 256) {
    uint2 p = stage[base + j];
    int pos = atomicAdd(&curs[p.y & 255], 1);
    col[pos] = (int)p.x;
  }
}

// ---------------- fused SAGE via MFMA, LDS weights + 4-burst gather ----------------
template <bool RELU>
__global__ __launch_bounds__(256) void sage_dual_kernel(
    const short* __restrict__ xsrcA, const short* __restrict__ xdstA,
    const int* __restrict__ offA, const int* __restrict__ colA,
    const float* __restrict__ WlA, const float* __restrict__ blA,
    const float* __restrict__ WrA, short* __restrict__ outA, int nA, int blkA,
    const short* __restrict__ xsrcB, const short* __restrict__ xdstB,
    const int* __restrict__ offB, const int* __restrict__ colB,
    const float* __restrict__ WlB, const float* __restrict__ blB,
    const float* __restrict__ WrB, short* __restrict__ outB, int nB) {
  bool isB = ((int)blockIdx.x >= blkA);
  int bid = isB ? (int)blockIdx.x - blkA : (int)blockIdx.x;
  const short* xsrc = isB ? xsrcB : xsrcA;
  const short* xdst = isB ? xdstB : xdstA;
  const int* off = isB ? offB : offA;
  const int* col = isB ? colB : colA;
  const float* Wl = isB ? WlB : WlA;
  const float* bl = isB ? blB : blA;
  const float* Wr = isB ? WrB : WrA;
  short* out = isB ? outB : outA;
  int n_dst = isB ? nB : nA;

  int t = threadIdx.x;
  int wave = t >> 6, lane = t & 63;
  int g = lane >> 4, c = lane & 15;

  __shared__ short8 lds_bw[4][4][64];
  for (int i = t; i < 4 * 4 * 64; i += 256) {
    int kt = i >> 8;
    int nn = (i >> 6) & 3;
    int ln = i & 63;
    int gg = ln >> 4, cc = ln & 15;
    const float* Wsrc = (kt < 2) ? Wl : Wr;
    int kbase = (kt & 1) * 32 + 8 * gg;
    short8 w;
#pragma unroll
    for (int j = 0; j < 8; ++j)
      w[j] = f2bf(Wsrc[(kbase + j) * H + 16 * nn + cc]);
    lds_bw[kt][nn][ln] = w;
  }
  __syncthreads();

  int node0 = (bid * 4 + wave) * 16;
  if (node0 >= n_dst) return;

  int mynode = node0 + c;
  int nd = (mynode < n_dst) ? mynode : 0;

  float blv[4];
#pragma unroll
  for (int n = 0; n < 4; ++n) blv[n] = bl[16 * n + c];

  const short8* pr = (const short8*)(xdst + (size_t)nd * H + 8 * g);
  short8 r0 = pr[0], r1 = pr[4];

  float m[16];
#pragma unroll
  for (int i = 0; i < 16; ++i) m[i] = 0.f;
  int beg = off[nd];
  int n_nb = off[nd + 1] - beg;
  for (int jb = 0; jb < n_nb; jb += 4) {
    int rem = n_nb - jb;
    int j1 = jb + (rem > 1 ? 1 : 0);
    int j2 = jb + (rem > 2 ? 2 : 0);
    int j3 = jb + (rem > 3 ? 3 : 0);
    int i0 = col[beg + jb];
    int i1 = col[beg + j1];
    int i2 = col[beg + j2];
    int i3 = col[beg + j3];
    const short8* p0 = (const short8*)(xsrc + (size_t)i0 * H + 8 * g);
    const short8* p1 = (const short8*)(xsrc + (size_t)i1 * H + 8 * g);
    const short8* p2 = (const short8*)(xsrc + (size_t)i2 * H + 8 * g);
    const short8* p3 = (const short8*)(xsrc + (size_t)i3 * H + 8 * g);
    short8 a0 = p0[0], b0 = p0[4];
    short8 a1 = p1[0], b1 = p1[4];
    short8 a2 = p2[0], b2 = p2[4];
    short8 a3 = p3[0], b3 = p3[4];
    acc16(m, a0, b0);
    if (rem > 1) acc16(m, a1, b1);
    if (rem > 2) acc16(m, a2, b2);
    if (rem > 3) acc16(m, a3, b3);
  }
  float invd = (n_nb > 0) ? 1.f / (float)n_nb : 1.f;
  f32x4 m0, m1, m2, m3;
#pragma unroll
  for (int i = 0; i < 4; ++i) {
    m0[i] = m[i] * invd;
    m1[i] = m[4 + i] * invd;
    m2[i] = m[8 + i] * invd;
    m3[i] = m[12 + i] * invd;
  }

  short8 af[4];
  af[0] = cvt8(m0, m1);
  af[1] = cvt8(m2, m3);
  af[2] = r0;
  af[3] = r1;

  f32x4 zero4 = {0.f, 0.f, 0.f, 0.f};
  f32x4 acc[4];
#pragma unroll
  for (int n = 0; n < 4; ++n) acc[n] = zero4;
#pragma unroll
  for (int kt = 0; kt < 4; ++kt)
#pragma unroll
    for (int n = 0; n < 4; ++n)
      acc[n] = __builtin_amdgcn_mfma_f32_16x16x32_bf16(af[kt], lds_bw[kt][n][lane], acc[n], 0, 0, 0);

#pragma unroll
  for (int n = 0; n < 4; ++n)
#pragma unroll
    for (int r = 0; r < 4; ++r) {
      float o = acc[n][r] + blv[n];
      if (RELU) o = fmaxf(o, 0.f);
      int row = node0 + 4 * g + r;
      if (row < n_dst) out[(size_t)row * H + 16 * n + c] = f2bf(o);
    }
}

// ---------------- edge classifier via MFMA, LDS weights + 2-deep tile pipeline --------
__global__ __launch_bounds__(256) void edge_mlp_mfma_kernel(
    const short* __restrict__ mch2, const short* __restrict__ mft2,
    const int* __restrict__ src, const int* __restrict__ dst,
    const float* __restrict__ W1, const float* __restrict__ b1,
    const float* __restrict__ W2, const float* __restrict__ b2,
    float* __restrict__ out, int E) {
  int t = threadIdx.x;
  int wave = t >> 6, lane = t & 63;
  int g = lane >> 4, c = lane & 15;

  __shared__ short8 lds_bw[4][4][64];
  for (int i = t; i < 4 * 4 * 64; i += 256) {
    int kt = i >> 8;
    int nn = (i >> 6) & 3;
    int ln = i & 63;
    int gg = ln >> 4, cc = ln & 15;
    int kbase = 32 * kt + 8 * gg;
    short8 w;
#pragma unroll
    for (int j = 0; j < 8; ++j)
      w[j] = f2bf(W1[(kbase + j) * H + 16 * nn + cc]);
    lds_bw[kt][nn][ln] = w;
  }
  __syncthreads();

  float b1v[4], w2v[4];
#pragma unroll
  for (int n = 0; n < 4; ++n) { b1v[n] = b1[16 * n + c]; w2v[n] = W2[16 * n + c]; }
  float b2v = b2[0];
  f32x4 zero4 = {0.f, 0.f, 0.f, 0.f};

  int ntiles = (E + 15) >> 4;
  int stride = gridDim.x * 4;
  int t0 = blockIdx.x * 4 + wave;
  if (t0 >= ntiles) return;

  auto loadIdx = [&](int tile, int& s, int& d) {
    int e = tile * 16 + c;
    int ee = (e < E) ? e : E - 1;
    s = src[ee];
    d = dst[ee];
  };
  auto loadRows = [&](int s, int d, short8* af) {
    const short8* pa = (const short8*)(mch2 + (size_t)s * H + 8 * g);
    const short8* pb = (const short8*)(mft2 + (size_t)d * H + 8 * g);
    af[0] = pa[0];
    af[1] = pa[4];
    af[2] = pb[0];
    af[3] = pb[4];
  };

  int sA, dA, sB, dB;
  short8 afA[4];
  loadIdx(t0, sA, dA);
  loadRows(sA, dA, afA);
  {
    int tB = t0 + stride;
    loadIdx((tB < ntiles) ? tB : (ntiles - 1), sB, dB);
  }

  for (int tile = t0; tile < ntiles; tile += stride) {
    short8 afB[4];
    loadRows(sB, dB, afB);
    int sC, dC;
    {
      int tC = tile + 2 * stride;
      loadIdx((tC < ntiles) ? tC : (ntiles - 1), sC, dC);
    }

    f32x4 acc[4];
#pragma unroll
    for (int n = 0; n < 4; ++n) acc[n] = zero4;
#pragma unroll
    for (int kt = 0; kt < 4; ++kt)
#pragma unroll
      for (int n = 0; n < 4; ++n)
        acc[n] = __builtin_amdgcn_mfma_f32_16x16x32_bf16(afA[kt], lds_bw[kt][n][lane], acc[n], 0, 0, 0);

    float part[4];
#pragma unroll
    for (int r = 0; r < 4; ++r) {
      float sum = 0.f;
#pragma unroll
      for (int n = 0; n < 4; ++n) {
        float v = acc[n][r] + b1v[n];
        v = fmaxf(v, 0.f);
        sum = fmaf(v, w2v[n], sum);
      }
      part[r] = sum;
    }
#pragma unroll
    for (int r = 0; r < 4; ++r) {
      part[r] += __shfl_xor(part[r], 1);
      part[r] += __shfl_xor(part[r], 2);
      part[r] += __shfl_xor(part[r], 4);
      part[r] += __shfl_xor(part[r], 8);
    }
    if (c < 4) {
      int eo = tile * 16 + 4 * g + c;
      float v = (c == 0) ? part[0] : (c == 1) ? part[1] : (c == 2) ? part[2] : part[3];
      if (eo < E) out[eo] = 1.f / (1.f + expf(-(v + b2v)));
    }

#pragma unroll
    for (int i = 0; i < 4; ++i) afA[i] = afB[i];
    sB = sC;
    dB = dC;
  }
}

extern "C" void kernel_launch(void* const* d_in, const int* in_sizes, int n_in,
                              void* d_out, int out_size, void* d_ws, size_t ws_size,
                              hipStream_t stream) {
  const float* x_mch = (const float*)d_in[0];
  const float* x_mft = (const float*)d_in[1];
  const int* eidx = (const int*)d_in[2];
  const int E = in_sizes[2] / 2;
  const int* src = eidx;
  const int* dst = eidx + E;
  const float* W_mch = (const float*)d_in[3];
  const float* b_mch = (const float*)d_in[4];
  const float* W_mft = (const float*)d_in[5];
  const float* b_mft = (const float*)d_in[6];
  const float* c1m_Wl = (const float*)d_in[7];
  const float* c1m_bl = (const float*)d_in[8];
  const float* c1m_Wr = (const float*)d_in[9];
  const float* c1r_Wl = (const float*)d_in[10];
  const float* c1r_bl = (const float*)d_in[11];
  const float* c1r_Wr = (const float*)d_in[12];
  const float* c2m_Wl = (const float*)d_in[13];
  const float* c2m_bl = (const float*)d_in[14];
  const float* c2m_Wr = (const float*)d_in[15];
  const float* c2r_Wl = (const float*)d_in[16];
  const float* c2r_bl = (const float*)d_in[17];
  const float* c2r_Wr = (const float*)d_in[18];
  const float* ec_W1 = (const float*)d_in[19];
  const float* ec_b1 = (const float*)d_in[20];
  const float* ec_W2 = (const float*)d_in[21];
  const float* ec_b2 = (const float*)d_in[22];

  const int n_mch = in_sizes[0] / D_IN;
  const int n_mft = in_sizes[1] / D_IN;
  const int nGS = (n_mch + 255) >> GSH;  // groups by src (mch)
  const int nGD = (n_mft + 255) >> GSH;  // groups by dst (mft)
  const int NB = (E + CHUNK - 1) / CHUNK;

  // ---- workspace layout ----
  char* ws = (char*)d_ws;
  auto alloc = [&](size_t bytes) {
    char* p = ws;
    ws += (bytes + 255) & ~(size_t)255;
    return p;
  };
  short* h_mch = (short*)alloc((size_t)n_mch * H * 2);
  short* h_mft = (short*)alloc((size_t)n_mft * H * 2);
  short* mch1 = (short*)alloc((size_t)n_mch * H * 2);
  short* mft1 = (short*)alloc((size_t)n_mft * H * 2);
  short* mch2 = (short*)alloc((size_t)n_mch * H * 2);
  short* mft2 = (short*)alloc((size_t)n_mft * H * 2);
  int* off_mch = (int*)alloc(((size_t)n_mch + 1) * 4);
  int* off_mft = (int*)alloc(((size_t)n_mft + 1) * 4);
  int* col_mch = (int*)alloc((size_t)E * 4);
  int* col_mft = (int*)alloc((size_t)E * 4);
  int* gcntS = (int*)alloc((size_t)MAXG * 4);
  int* gcntD = (int*)alloc((size_t)MAXG * 4);
  int* GoffS = (int*)alloc(((size_t)MAXG + 1) * 4);
  int* GoffD = (int*)alloc(((size_t)MAXG + 1) * 4);
  int* baseS = (int*)alloc((size_t)NB * nGS * 4);
  int* baseD = (int*)alloc((size_t)NB * nGD * 4);
  uint2* stageS = (uint2*)alloc((size_t)E * 8);
  uint2* stageD = (uint2*)alloc((size_t)E * 8);

  float* out = (float*)d_out;

  // ---- CSR build v4 (block-aggregated counting sort) ----
  hipMemsetAsync(gcntS, 0, (size_t)MAXG * 4, stream);
  hipMemsetAsync(gcntD, 0, (size_t)MAXG * 4, stream);
  group_count_kernel<<<NB, 256, 0, stream>>>(src, dst, gcntS, gcntD, baseS, baseD,
                                             nGS, nGD, E);
  goff_scan_kernel<<<2, 512, 0, stream>>>(gcntS, GoffS, nGS, gcntD, GoffD, nGD);
  stage_scatter_kernel<<<NB, 256, 0, stream>>>(src, dst, GoffS, GoffD, baseS, baseD,
                                               stageS, stageD, nGS, nGD, E);
  finalize_group_kernel<<<nGS + nGD, 256, 0, stream>>>(
      stageS, GoffS, nGS, n_mch, off_mch, col_mch,
      stageD, GoffD, n_mft, off_mft, col_mft, E);

  // ---- input projections ----
  {
    int blk = ((n_mch * H) + 255) / 256;
    proj_kernel<<<blk, 256, 0, stream>>>(x_mch, W_mch, b_mch, h_mch, n_mch);
    blk = ((n_mft * H) + 255) / 256;
    proj_kernel<<<blk, 256, 0, stream>>>(x_mft, W_mft, b_mft, h_mft, n_mft);
  }

  // ---- convs (MFMA, both directions per launch) ----
  {
    int tiles_mft = (n_mft + 15) / 16;
    int tiles_mch = (n_mch + 15) / 16;
    int blkA = (tiles_mft + 3) / 4;
    int blkB = (tiles_mch + 3) / 4;
    sage_dual_kernel<true><<<blkA + blkB, 256, 0, stream>>>(
        h_mch, h_mft, off_mft, col_mft, c1m_Wl, c1m_bl, c1m_Wr, mft1, n_mft, blkA,
        h_mft, h_mch, off_mch, col_mch, c1r_Wl, c1r_bl, c1r_Wr, mch1, n_mch);
    sage_dual_kernel<false><<<blkA + blkB, 256, 0, stream>>>(
        mch1, mft1, off_mft, col_mft, c2m_Wl, c2m_bl, c2m_Wr, mft2, n_mft, blkA,
        mft1, mch1, off_mch, col_mch, c2r_Wl, c2r_bl, c2r_Wr, mch2, n_mch);
  }

  // ---- edge classifier (MFMA) ----
  {
    edge_mlp_mfma_kernel<<<2048, 256, 0, stream>>>(mch2, mft2, src, dst,
                                                   ec_W1, ec_b1, ec_W2, ec_b2, out, E);
  }
}